// Round 2
// baseline (124.309 us; speedup 1.0000x reference)
//
#include <hip/hip_runtime.h>
#include <hip/hip_bf16.h>

// B=128, LQ=32, LD=256, HID=768, DIM=128
typedef __attribute__((ext_vector_type(8))) short short8;
typedef __attribute__((ext_vector_type(4))) short short4v;
typedef __attribute__((ext_vector_type(4))) float f32x4;

#define MFMA16(a, b, c) __builtin_amdgcn_mfma_f32_16x16x32_bf16(a, b, c, 0, 0, 0)

__device__ __forceinline__ short f2bf(float f) {
    union { float f; unsigned u; } x; x.f = f;
    unsigned r = x.u + 0x7fffu + ((x.u >> 16) & 1u);  // RNE
    return (short)(r >> 16);
}

// ---------------------------------------------------------------------------
// Kernel 1 (rewritten): P[row][dim] = l2norm( X[row,:768] @ W[dim,:768]^T )
// GEMM mapping: A = X rows (M), B = W (N=dim), K = hid.
// Block: 64 rows x 128 dims, BK=64 (12 K-steps), 4 waves each 16 rows x 128 dims.
// Register-prefetch of chunk k+1 overlaps MFMA of chunk k (T14 pattern).
// ---------------------------------------------------------------------------
__global__ __launch_bounds__(256) void proj_norm_kernel(
    const float* __restrict__ qh, const float* __restrict__ dh,
    const float* __restrict__ W, const int* __restrict__ dmask,
    unsigned short* __restrict__ Qb, unsigned short* __restrict__ Db)
{
    __shared__ __align__(16) short Xlds[64][72];    // 64 rows x (64 k + 8 pad)
    __shared__ __align__(16) short Wlds[128][72];   // 128 dims x (64 k + 8 pad)

    const int tid = threadIdx.x;
    const int wave = tid >> 6, lane = tid & 63;
    const int l = lane & 15, g = lane >> 4;

    const int rowbase = blockIdx.x * 64;            // 0..36863; Q first 4096
    const bool isQ = rowbase < 4096;
    const float* X = isQ ? qh : dh;
    const int prow = isQ ? rowbase : rowbase - 4096;

    // staging assignment: X 64x64 by 4 thr/row (16 fl each); W 128x64 by 2 thr/row (32 fl)
    const int xrow = tid >> 2, xq = tid & 3;
    const int wrow = tid >> 1, wh = tid & 1;
    const float* xsrc = X + (size_t)(prow + xrow) * 768 + xq * 16;
    const float* wsrc = W + (size_t)wrow * 768 + wh * 32;

    float4 xr[4], wr[8];
    #pragma unroll
    for (int i = 0; i < 4; ++i) xr[i] = reinterpret_cast<const float4*>(xsrc)[i];
    #pragma unroll
    for (int i = 0; i < 8; ++i) wr[i] = reinterpret_cast<const float4*>(wsrc)[i];
    xsrc += 64; wsrc += 64;

    f32x4 acc[8];
    #pragma unroll
    for (int n = 0; n < 8; ++n) acc[n] = (f32x4)(0.0f);

    for (int k = 0; k < 12; ++k) {
        // --- cvt staged regs -> LDS bf16 ---
        {
            short8 v0, v1;
            v0[0]=f2bf(xr[0].x); v0[1]=f2bf(xr[0].y); v0[2]=f2bf(xr[0].z); v0[3]=f2bf(xr[0].w);
            v0[4]=f2bf(xr[1].x); v0[5]=f2bf(xr[1].y); v0[6]=f2bf(xr[1].z); v0[7]=f2bf(xr[1].w);
            v1[0]=f2bf(xr[2].x); v1[1]=f2bf(xr[2].y); v1[2]=f2bf(xr[2].z); v1[3]=f2bf(xr[2].w);
            v1[4]=f2bf(xr[3].x); v1[5]=f2bf(xr[3].y); v1[6]=f2bf(xr[3].z); v1[7]=f2bf(xr[3].w);
            short* dst = &Xlds[xrow][xq * 16];
            reinterpret_cast<short8*>(dst)[0] = v0;
            reinterpret_cast<short8*>(dst)[1] = v1;
        }
        {
            #pragma unroll
            for (int h = 0; h < 2; ++h) {
                short8 v;
                v[0]=f2bf(wr[h*2+0].x); v[1]=f2bf(wr[h*2+0].y); v[2]=f2bf(wr[h*2+0].z); v[3]=f2bf(wr[h*2+0].w);
                v[4]=f2bf(wr[h*2+1].x); v[5]=f2bf(wr[h*2+1].y); v[6]=f2bf(wr[h*2+1].z); v[7]=f2bf(wr[h*2+1].w);
                reinterpret_cast<short8*>(&Wlds[wrow][wh * 32])[h] = v;
                short8 u;
                u[0]=f2bf(wr[h*2+4].x); u[1]=f2bf(wr[h*2+4].y); u[2]=f2bf(wr[h*2+4].z); u[3]=f2bf(wr[h*2+4].w);
                u[4]=f2bf(wr[h*2+5].x); u[5]=f2bf(wr[h*2+5].y); u[6]=f2bf(wr[h*2+5].z); u[7]=f2bf(wr[h*2+5].w);
                reinterpret_cast<short8*>(&Wlds[wrow][wh * 32 + 16])[h] = u;
            }
        }
        __syncthreads();

        // --- issue prefetch of chunk k+1 (overlaps MFMAs below) ---
        if (k < 11) {
            #pragma unroll
            for (int i = 0; i < 4; ++i) xr[i] = reinterpret_cast<const float4*>(xsrc)[i];
            #pragma unroll
            for (int i = 0; i < 8; ++i) wr[i] = reinterpret_cast<const float4*>(wsrc)[i];
            xsrc += 64; wsrc += 64;
        }

        // --- compute: wave owns rows wave*16..+15, all 128 dims ---
        #pragma unroll
        for (int ks = 0; ks < 2; ++ks) {
            short8 af = *reinterpret_cast<const short8*>(&Xlds[wave * 16 + l][ks * 32 + g * 8]);
            #pragma unroll
            for (int n = 0; n < 8; ++n) {
                short8 bf = *reinterpret_cast<const short8*>(&Wlds[n * 16 + l][ks * 32 + g * 8]);
                acc[n] = MFMA16(af, bf, acc[n]);
            }
        }
        __syncthreads();
    }

    // --- L2 norm: lane holds C[row=g*4+r][dim=n*16+l] in acc[n][r] ---
    float rn[4];
    #pragma unroll
    for (int r = 0; r < 4; ++r) {
        float ss = 0.f;
        #pragma unroll
        for (int n = 0; n < 8; ++n) ss += acc[n][r] * acc[n][r];
        ss += __shfl_xor(ss, 1);
        ss += __shfl_xor(ss, 2);
        ss += __shfl_xor(ss, 4);
        ss += __shfl_xor(ss, 8);
        float v = rsqrtf(ss);
        const int row = prow + wave * 16 + g * 4 + r;
        if (!isQ && dmask[row] == 0) v = 0.f;      // zero masked doc tokens
        rn[r] = v;
    }

    unsigned short* P = isQ ? Qb : Db;
    #pragma unroll
    for (int n = 0; n < 8; ++n)
        #pragma unroll
        for (int r = 0; r < 4; ++r) {
            const int row = prow + wave * 16 + g * 4 + r;
            P[(size_t)row * 128 + n * 16 + l] = (unsigned short)f2bf(acc[n][r] * rn[r]);
        }
}

// ---------------------------------------------------------------------------
// Kernel 2 (unchanged): out[b][c] = sum_q max_k(valid) Q[b,q,:] . D[c,k,:]
// ---------------------------------------------------------------------------
__global__ __launch_bounds__(256) void maxsim_kernel(
    const unsigned short* __restrict__ Qb, const unsigned short* __restrict__ Db,
    const int* __restrict__ dmask, float* __restrict__ out)
{
    __shared__ __align__(16) short Dlds[256][136];  // 128 + 8 pad -> 2-way conflicts only

    const int tid = threadIdx.x;
    const int wave = tid >> 6, lane = tid & 63;
    const int l = lane & 15, g = lane >> 4;
    const int c = blockIdx.x & 127;
    const int bg = blockIdx.x >> 7;

    // --- stage D_c (256 tokens x 128 dims bf16 = 64KB), coalesced ---
    {
        const short8* src = reinterpret_cast<const short8*>(Db + (size_t)c * 256 * 128);
        #pragma unroll
        for (int i = 0; i < 16; ++i) {
            int idx = i * 256 + tid;            // 16B-chunk index
            short8 v = src[idx];
            int row = idx >> 4, col = idx & 15;
            *reinterpret_cast<short8*>(&Dlds[row][col * 8]) = v;
        }
    }
    // --- per-lane validity bits: token t = n*16 + l, n=0..15 ---
    unsigned vmask = 0;
    {
        const int* dm = dmask + c * 256;
        #pragma unroll
        for (int n = 0; n < 16; ++n) vmask |= (dm[n * 16 + l] != 0 ? 1u : 0u) << n;
    }
    __syncthreads();

    for (int ib = 0; ib < 8; ++ib) {
        const int b = bg * 32 + wave * 8 + ib;

        // A fragments: Q[b, m*16+l, ks*32 + g*8 + 0..7], L2-resident
        short8 a[2][4];
        const unsigned short* qp = Qb + (size_t)b * 32 * 128;
        #pragma unroll
        for (int m = 0; m < 2; ++m)
            #pragma unroll
            for (int ks = 0; ks < 4; ++ks)
                a[m][ks] = *reinterpret_cast<const short8*>(qp + (m * 16 + l) * 128 + ks * 32 + g * 8);

        float best[2][4];
        #pragma unroll
        for (int m = 0; m < 2; ++m)
            #pragma unroll
            for (int r = 0; r < 4; ++r) best[m][r] = -1e30f;

        // two halves of 8 token-tiles each (keeps acc at 64 VGPRs)
        #pragma unroll
        for (int half = 0; half < 2; ++half) {
            f32x4 acc[2][8];
            #pragma unroll
            for (int m = 0; m < 2; ++m)
                #pragma unroll
                for (int n = 0; n < 8; ++n) acc[m][n] = (f32x4)(0.f);

            #pragma unroll
            for (int ks = 0; ks < 4; ++ks) {
                #pragma unroll
                for (int n = 0; n < 8; ++n) {
                    const int t = (half * 8 + n) * 16 + l;
                    short8 bf = *reinterpret_cast<const short8*>(&Dlds[t][ks * 32 + g * 8]);
                    acc[0][n] = MFMA16(a[0][ks], bf, acc[0][n]);
                    acc[1][n] = MFMA16(a[1][ks], bf, acc[1][n]);
                }
            }
            // masked max over this half's token tiles (in-lane)
            #pragma unroll
            for (int n = 0; n < 8; ++n) {
                const bool valid = (vmask >> (half * 8 + n)) & 1;
                #pragma unroll
                for (int m = 0; m < 2; ++m)
                    #pragma unroll
                    for (int r = 0; r < 4; ++r) {
                        float s = valid ? acc[m][n][r] : -1e30f;
                        best[m][r] = fmaxf(best[m][r], s);
                    }
            }
        }

        // max over the 16 lanes of the group (tokens t = n*16 + l), then sum over q
        float sum = 0.f;
        #pragma unroll
        for (int m = 0; m < 2; ++m)
            #pragma unroll
            for (int r = 0; r < 4; ++r) {
                float v = best[m][r];
                v = fmaxf(v, __shfl_xor(v, 1));
                v = fmaxf(v, __shfl_xor(v, 2));
                v = fmaxf(v, __shfl_xor(v, 4));
                v = fmaxf(v, __shfl_xor(v, 8));
                sum += v;   // q = m*16 + g*4 + r
            }
        sum += __shfl_xor(sum, 16);  // sum over lane groups (q coverage 0..31)
        sum += __shfl_xor(sum, 32);
        if (lane == 0) out[b * 128 + c] = sum;
    }
}

extern "C" void kernel_launch(void* const* d_in, const int* in_sizes, int n_in,
                              void* d_out, int out_size, void* d_ws, size_t ws_size,
                              hipStream_t stream)
{
    const float* qh    = (const float*)d_in[0];   // [128,32,768]
    const float* dh    = (const float*)d_in[1];   // [128,256,768]
    const float* W     = (const float*)d_in[2];   // [128,768]
    const int*   dmask = (const int*)d_in[3];     // [128,256]
    float* out = (float*)d_out;                   // [128,128]

    unsigned short* Qb = (unsigned short*)d_ws;        // 4096 x 128 bf16 (1 MB)
    unsigned short* Db = Qb + 4096 * 128;              // 32768 x 128 bf16 (8 MB)

    // 36864 rows / 64 rows-per-block = 576 blocks
    hipLaunchKernelGGL(proj_norm_kernel, dim3(576), dim3(256), 0, stream,
                       qh, dh, W, dmask, Qb, Db);
    // 128 docs x 4 b-groups = 512 blocks
    hipLaunchKernelGGL(maxsim_kernel, dim3(512), dim3(256), 0, stream,
                       Qb, Db, dmask, out);
}